// Round 13
// baseline (101.442 us; speedup 1.0000x reference)
//
#include <hip/hip_runtime.h>
#include <hip/hip_fp8.h>
#include <math.h>

// ContrastiveLoss — x (8,128,16,8,8) fp32 (4 MB).
// feats[n,f] = x[b*131072 + f*1024 + r], n=(b<<10)|r, N=8192, F=128.
// loss = 10 + ln( sum_{i!=j} exp(10*dot(x̂_i,x̂_j) - 10) )   (unit rows => s<=10)
//
// Round 22: FUSE FINAL INTO GRAM (single variable on the frozen R11 body).
// R12's XCD swizzle was null -> cold phase is fabric-latency-bound, not
// locality-bound; tile reshaping to cut cold traffic loses to grid
// granularity (528 blocks -> +45% makespan tail). Budget: warm 8.7 (MFMA
// floor 5.8 + epilogue 3.5), cold 6.0, fixed 53.4 of which ~9 us is launch
// gaps across 3 dispatches. Cheapest lever: drop one dispatch. Counter +
// last-block fixed-order f64 reduction (bit-exact in R1/R2; their slowness
// was gram-body spills, absent in this 52-VGPR body). Swizzle reverted.
// Failure mode (codegen perturbation) detectable: gram in top-5 / WRITE_SIZE.
//
// fp8 swizzled layout (verified R7/R8, absmax 0): row-group rg=n>>4 (16 rows,
// 2KB). 16B chunk (t8*64 + q*16 + r) holds bytes[half*8+j] =
// x̂[row r][k = t8*64 + half*32 + q*8 + j]. C/D: col=lane&15,
// row=(lane>>4)*4+reg (dtype-independent, verified).
//
// ws: partials float[2080] @0; counter u32 @16384; Xs fp8 @131072 (1MB).

#define NMACR 2080   // 64*65/2 upper-triangle 128x128 macro-tiles

typedef __attribute__((ext_vector_type(4))) float f32x4;
typedef __attribute__((ext_vector_type(2))) long i64x2;

#if __has_builtin(__builtin_amdgcn_exp2f)
#define EXP2F(x) __builtin_amdgcn_exp2f(x)
#else
#define EXP2F(x) exp2f(x)
#endif

__device__ inline unsigned int pk_fp8(float f0, float f1, float f2, float f3) {
#if __has_builtin(__builtin_amdgcn_cvt_pk_fp8_f32)
    unsigned int r = 0;
    r = __builtin_amdgcn_cvt_pk_fp8_f32(f0, f1, r, false);  // bytes 0,1
    r = __builtin_amdgcn_cvt_pk_fp8_f32(f2, f3, r, true);   // bytes 2,3
    return r;
#else
    union { unsigned char b[4]; unsigned int u; } v;
    v.b[0] = __hip_fp8_e4m3(f0).__x; v.b[1] = __hip_fp8_e4m3(f1).__x;
    v.b[2] = __hip_fp8_e4m3(f2).__x; v.b[3] = __hip_fp8_e4m3(f3).__x;
    return v.u;
#endif
}

// ---------------------------------------------------------------------------
// Kernel 1: normalize + fp8 swizzle. Block = 32 rows (2 row-groups).
// Also zero-inits the gram completion counter (ws is poisoned between runs).
// ---------------------------------------------------------------------------
__global__ __launch_bounds__(256)
void normalize_kernel(const float* __restrict__ x, unsigned char* __restrict__ Xs,
                      unsigned int* __restrict__ counter) {
    if (blockIdx.x == 0 && threadIdx.x == 0) counter[0] = 0u;
    __shared__ float ldsf[128][33];
    __shared__ float ssred[8][32];
    __shared__ float invs[32];
    const int tid = threadIdx.x;
    const int b  = blockIdx.x >> 5;
    const int r0 = (blockIdx.x & 31) * 32;
    const int rl = tid & 31, fp = tid >> 5;       // row-in-block, f-slot
    const float* px = x + b * 131072 + r0 + rl;
    float ss = 0.f;
#pragma unroll
    for (int j = 0; j < 16; ++j) {
        int f = fp * 16 + j;
        float v = px[f * 1024];
        ldsf[f][rl] = v;
        ss = fmaf(v, v, ss);
    }
    ssred[fp][rl] = ss;
    __syncthreads();
    if (tid < 32) {
        float s = 0.f;
#pragma unroll
        for (int k = 0; k < 8; ++k) s += ssred[k][tid];
        invs[tid] = 1.0f / fmaxf(sqrtf(s), 1e-12f);
    }
    __syncthreads();
    {   // one 16B chunk per thread, consecutive tid -> consecutive chunks
        const int c   = tid;
        const int rgl = c >> 7;                   // local row-group 0..1
        const int cc  = c & 127;                  // chunk within row-group
        const int t8  = (cc >> 6) & 1, q = (cc >> 4) & 3, r = cc & 15;
        const int row = rgl * 16 + r;             // local row 0..31
        const float inv = invs[row];
        union { unsigned int w[4]; int4 v; } u;
#pragma unroll
        for (int half = 0; half < 2; ++half) {
            const int k0 = t8 * 64 + half * 32 + q * 8;
            u.w[half * 2 + 0] = pk_fp8(ldsf[k0 + 0][row] * inv, ldsf[k0 + 1][row] * inv,
                                       ldsf[k0 + 2][row] * inv, ldsf[k0 + 3][row] * inv);
            u.w[half * 2 + 1] = pk_fp8(ldsf[k0 + 4][row] * inv, ldsf[k0 + 5][row] * inv,
                                       ldsf[k0 + 6][row] * inv, ldsf[k0 + 7][row] * inv);
        }
        const int rgg = blockIdx.x * 2 + rgl;     // global row-group
        ((int4*)Xs)[rgg * 128 + cc] = u.v;
    }
}

// ---------------------------------------------------------------------------
// Kernel 2: macro-tile gram (R11 body, B-only LDS, natural tile order) +
// fused final reduction: per-block partial -> device counter; the LAST
// block performs the identical fixed-order f64 reduction (deterministic).
// ---------------------------------------------------------------------------
__global__ __launch_bounds__(256)
void gram_lse_kernel(const i64x2* __restrict__ Xs, float* __restrict__ partials,
                     unsigned int* __restrict__ counter, float* __restrict__ out) {
    const int bk = blockIdx.x;
    const int tid = threadIdx.x;
    const int lane = tid & 63, w = tid >> 6;
    const int ga = (w & 1) * 2;                  // A rg offset within sub-tile
    const int gb = (w >> 1) * 2;                 // B rg offset within sub-tile
    const int quad = lane >> 4, colL = lane & 15;
    const float C = 14.426950408889634f;         // 10*log2(e)

    // closed-form macro decode: tiles_before(I) = I*(129-I)/2  (64 rows)
    int I;
    {
        const int t = bk;
        I = (int)((129.0 - sqrt(16641.0 - 8.0 * (double)t)) * 0.5);
        if (I < 0) I = 0;
        while ((((I + 1) * (128 - I)) >> 1) <= t) ++I;   // tb(I+1) <= t
        while (((I * (129 - I)) >> 1) > t) --I;          // tb(I)   >  t
    }
    const int J = I + (bk - ((I * (129 - I)) >> 1));
    const bool diagM = (I == J);

    // A fragments: DIRECT global loads (private per wave; no LDS relay).
    // rg = 8I + ti*4 + ga + g
    i64x2 avv[2][2][2];
#pragma unroll
    for (int ti = 0; ti < 2; ++ti)
#pragma unroll
        for (int g = 0; g < 2; ++g)
#pragma unroll
            for (int t8 = 0; t8 < 2; ++t8)
                avv[ti][g][t8] =
                    Xs[(I * 8 + ti * 4 + ga + g) * 128 + t8 * 64 + lane];

    // B panel staged in LDS (shared: each rg read by 2 waves, twice)
    __shared__ i64x2 ldsB[1024];                 // 16KB: B panel (8 rgs)
    {
        const i64x2* pb = Xs + J * 1024;         // panel = contiguous Xs slice
#pragma unroll
        for (int i = 0; i < 4; ++i)
            ldsB[tid + i * 256] = pb[tid + i * 256];
    }
    __syncthreads();

    float wsum = 0.f;
#pragma unroll
    for (int tj = 0; tj < 2; ++tj) {
        i64x2 bvv[2][2];
#pragma unroll
        for (int g = 0; g < 2; ++g)
#pragma unroll
            for (int t8 = 0; t8 < 2; ++t8)
                bvv[g][t8] = ldsB[(tj * 4 + gb + g) * 128 + t8 * 64 + lane];

#pragma unroll
        for (int ti = 0; ti < 2; ++ti) {
            if (diagM && ti > tj) continue;      // below-diagonal sub: skip
            const bool dsub = diagM && (ti == tj);

            f32x4 acc[2][2];
#pragma unroll
            for (int i = 0; i < 2; ++i)
#pragma unroll
                for (int j = 0; j < 2; ++j) acc[i][j] = (f32x4){0.f, 0.f, 0.f, 0.f};
#pragma unroll
            for (int t = 0; t < 4; ++t) {        // K-steps of 32
                const int th = t >> 1, tl = t & 1;
                long aL[2], bL[2];
#pragma unroll
                for (int g = 0; g < 2; ++g) {
                    aL[g] = avv[ti][g][th][tl];
                    bL[g] = bvv[g][th][tl];
                }
#pragma unroll
                for (int i = 0; i < 2; ++i)
#pragma unroll
                    for (int j = 0; j < 2; ++j)
                        acc[i][j] = __builtin_amdgcn_mfma_f32_16x16x32_fp8_fp8(
                            aL[i], bL[j], acc[i][j], 0, 0, 0);
            }

            // C/D: col=lane&15, row=(lane>>4)*4+reg (verified)
            float lsum = 0.f;
#pragma unroll
            for (int i = 0; i < 2; ++i) {
                const int rbase = (ga + i) * 16 + quad * 4;   // row in sub-tile
#pragma unroll
                for (int j = 0; j < 2; ++j) {
                    const int cbase = (gb + j) * 16 + colL;   // col in sub-tile
#pragma unroll
                    for (int g = 0; g < 4; ++g) {
                        if (dsub && (rbase + g == cbase)) continue;
                        lsum += EXP2F(fmaf(C, acc[i][j][g], -C));
                    }
                }
            }
            wsum += dsub ? lsum : 2.0f * lsum;   // symmetry weight
        }
    }

#pragma unroll
    for (int o = 32; o > 0; o >>= 1) wsum += __shfl_down(wsum, o, 64);
    __shared__ float red[4];
    __shared__ bool last;
    if (lane == 0) red[w] = wsum;
    __syncthreads();
    if (tid == 0) {
        partials[bk] = red[0] + red[1] + red[2] + red[3];
        __threadfence();                          // publish partial (cross-XCD)
        last = (atomicAdd(counter, 1u) == NMACR - 1);
    }
    __syncthreads();
    if (last) {
        __threadfence();                          // acquire all partials
        double s = 0.0;
        for (int i = tid; i < NMACR; i += 256) s += (double)partials[i];
#pragma unroll
        for (int o = 32; o > 0; o >>= 1) s += __shfl_down(s, o, 64);
        __shared__ double dred[4];
        if (lane == 0) dred[w] = s;
        __syncthreads();
        if (tid == 0)
            out[0] = (float)(10.0 + log(dred[0] + dred[1] + dred[2] + dred[3]));
    }
}

extern "C" void kernel_launch(void* const* d_in, const int* in_sizes, int n_in,
                              void* d_out, int out_size, void* d_ws, size_t ws_size,
                              hipStream_t stream) {
    const float* x = (const float*)d_in[0];
    float* out = (float*)d_out;
    float* partials = (float*)d_ws;                           // 2080 floats @0
    unsigned int* counter = (unsigned int*)((char*)d_ws + 16384);
    unsigned char* Xs = (unsigned char*)d_ws + 131072;        // 1MB fp8 X̂

    normalize_kernel<<<256, 256, 0, stream>>>(x, Xs, counter);
    gram_lse_kernel<<<NMACR, 256, 0, stream>>>((const i64x2*)Xs, partials, counter, out);
}

// Round 14
// 92.628 us; speedup vs baseline: 1.0952x; 1.0952x over previous
//
#include <hip/hip_runtime.h>
#include <hip/hip_fp8.h>
#include <math.h>

// ContrastiveLoss — x (8,128,16,8,8) fp32 (4 MB).
// feats[n,f] = x[b*131072 + f*1024 + r], n=(b<<10)|r, N=8192, F=128.
// loss = 10 + ln( sum_{i!=j} exp(10*dot(x̂_i,x̂_j) - 10) )   (unit rows => s<=10)
//
// Round 23: FUSION WITHOUT L2 INVALIDATION. R13 diagnosis: fused gram ran
// 3.3x slow (49 µs, MfmaUtil 6%, no spills, normal FETCH) because each
// block's __threadfence() emits buffer_wbl2 + buffer_inv at agent scope —
// buffer_inv INVALIDATES the XCD's L2. 2080 invalidates = continuous L2
// flush => every Xs panel read became an IF$/fabric miss (FETCH stayed low:
// refills come from L3, not HBM). Same mechanism explains R1/R2 regressions.
// Fix (single change vs R13): per-block publish uses a RELEASE-scoped atomic
//   __hip_atomic_fetch_add(counter, 1, __ATOMIC_RELEASE, AGENT)
// -> emits only the wbl2 writeback (dirty set = 4B of partials), NO inv.
// The one acquire __threadfence() stays in the LAST block only (single
// invalidate, required to read other XCDs' partials). Release->acquire via
// the counter keeps the fixed-order f64 reduction correct & deterministic.
//
// fp8 swizzled layout (verified R7/R8, absmax 0): row-group rg=n>>4 (16 rows,
// 2KB). 16B chunk (t8*64 + q*16 + r) holds bytes[half*8+j] =
// x̂[row r][k = t8*64 + half*32 + q*8 + j]. C/D: col=lane&15,
// row=(lane>>4)*4+reg (dtype-independent, verified).
//
// ws: partials float[2080] @0; counter u32 @16384; Xs fp8 @131072 (1MB).

#define NMACR 2080   // 64*65/2 upper-triangle 128x128 macro-tiles

typedef __attribute__((ext_vector_type(4))) float f32x4;
typedef __attribute__((ext_vector_type(2))) long i64x2;

#if __has_builtin(__builtin_amdgcn_exp2f)
#define EXP2F(x) __builtin_amdgcn_exp2f(x)
#else
#define EXP2F(x) exp2f(x)
#endif

__device__ inline unsigned int pk_fp8(float f0, float f1, float f2, float f3) {
#if __has_builtin(__builtin_amdgcn_cvt_pk_fp8_f32)
    unsigned int r = 0;
    r = __builtin_amdgcn_cvt_pk_fp8_f32(f0, f1, r, false);  // bytes 0,1
    r = __builtin_amdgcn_cvt_pk_fp8_f32(f2, f3, r, true);   // bytes 2,3
    return r;
#else
    union { unsigned char b[4]; unsigned int u; } v;
    v.b[0] = __hip_fp8_e4m3(f0).__x; v.b[1] = __hip_fp8_e4m3(f1).__x;
    v.b[2] = __hip_fp8_e4m3(f2).__x; v.b[3] = __hip_fp8_e4m3(f3).__x;
    return v.u;
#endif
}

// ---------------------------------------------------------------------------
// Kernel 1: normalize + fp8 swizzle. Block = 32 rows (2 row-groups).
// Also zero-inits the gram completion counter (ws is poisoned between runs).
// ---------------------------------------------------------------------------
__global__ __launch_bounds__(256)
void normalize_kernel(const float* __restrict__ x, unsigned char* __restrict__ Xs,
                      unsigned int* __restrict__ counter) {
    if (blockIdx.x == 0 && threadIdx.x == 0) counter[0] = 0u;
    __shared__ float ldsf[128][33];
    __shared__ float ssred[8][32];
    __shared__ float invs[32];
    const int tid = threadIdx.x;
    const int b  = blockIdx.x >> 5;
    const int r0 = (blockIdx.x & 31) * 32;
    const int rl = tid & 31, fp = tid >> 5;       // row-in-block, f-slot
    const float* px = x + b * 131072 + r0 + rl;
    float ss = 0.f;
#pragma unroll
    for (int j = 0; j < 16; ++j) {
        int f = fp * 16 + j;
        float v = px[f * 1024];
        ldsf[f][rl] = v;
        ss = fmaf(v, v, ss);
    }
    ssred[fp][rl] = ss;
    __syncthreads();
    if (tid < 32) {
        float s = 0.f;
#pragma unroll
        for (int k = 0; k < 8; ++k) s += ssred[k][tid];
        invs[tid] = 1.0f / fmaxf(sqrtf(s), 1e-12f);
    }
    __syncthreads();
    {   // one 16B chunk per thread, consecutive tid -> consecutive chunks
        const int c   = tid;
        const int rgl = c >> 7;                   // local row-group 0..1
        const int cc  = c & 127;                  // chunk within row-group
        const int t8  = (cc >> 6) & 1, q = (cc >> 4) & 3, r = cc & 15;
        const int row = rgl * 16 + r;             // local row 0..31
        const float inv = invs[row];
        union { unsigned int w[4]; int4 v; } u;
#pragma unroll
        for (int half = 0; half < 2; ++half) {
            const int k0 = t8 * 64 + half * 32 + q * 8;
            u.w[half * 2 + 0] = pk_fp8(ldsf[k0 + 0][row] * inv, ldsf[k0 + 1][row] * inv,
                                       ldsf[k0 + 2][row] * inv, ldsf[k0 + 3][row] * inv);
            u.w[half * 2 + 1] = pk_fp8(ldsf[k0 + 4][row] * inv, ldsf[k0 + 5][row] * inv,
                                       ldsf[k0 + 6][row] * inv, ldsf[k0 + 7][row] * inv);
        }
        const int rgg = blockIdx.x * 2 + rgl;     // global row-group
        ((int4*)Xs)[rgg * 128 + cc] = u.v;
    }
}

// ---------------------------------------------------------------------------
// Kernel 2: macro-tile gram (R11 body, B-only LDS) + fused final reduction.
// Per-block publish: RELEASE atomic (wbl2 only, no L2 invalidate). Last
// block: one acquire __threadfence(), then fixed-order f64 reduction.
// ---------------------------------------------------------------------------
__global__ __launch_bounds__(256)
void gram_lse_kernel(const i64x2* __restrict__ Xs, float* __restrict__ partials,
                     unsigned int* __restrict__ counter, float* __restrict__ out) {
    const int bk = blockIdx.x;
    const int tid = threadIdx.x;
    const int lane = tid & 63, w = tid >> 6;
    const int ga = (w & 1) * 2;                  // A rg offset within sub-tile
    const int gb = (w >> 1) * 2;                 // B rg offset within sub-tile
    const int quad = lane >> 4, colL = lane & 15;
    const float C = 14.426950408889634f;         // 10*log2(e)

    // closed-form macro decode: tiles_before(I) = I*(129-I)/2  (64 rows)
    int I;
    {
        const int t = bk;
        I = (int)((129.0 - sqrt(16641.0 - 8.0 * (double)t)) * 0.5);
        if (I < 0) I = 0;
        while ((((I + 1) * (128 - I)) >> 1) <= t) ++I;   // tb(I+1) <= t
        while (((I * (129 - I)) >> 1) > t) --I;          // tb(I)   >  t
    }
    const int J = I + (bk - ((I * (129 - I)) >> 1));
    const bool diagM = (I == J);

    // A fragments: DIRECT global loads (private per wave; no LDS relay).
    // rg = 8I + ti*4 + ga + g
    i64x2 avv[2][2][2];
#pragma unroll
    for (int ti = 0; ti < 2; ++ti)
#pragma unroll
        for (int g = 0; g < 2; ++g)
#pragma unroll
            for (int t8 = 0; t8 < 2; ++t8)
                avv[ti][g][t8] =
                    Xs[(I * 8 + ti * 4 + ga + g) * 128 + t8 * 64 + lane];

    // B panel staged in LDS (shared: each rg read by 2 waves, twice)
    __shared__ i64x2 ldsB[1024];                 // 16KB: B panel (8 rgs)
    {
        const i64x2* pb = Xs + J * 1024;         // panel = contiguous Xs slice
#pragma unroll
        for (int i = 0; i < 4; ++i)
            ldsB[tid + i * 256] = pb[tid + i * 256];
    }
    __syncthreads();

    float wsum = 0.f;
#pragma unroll
    for (int tj = 0; tj < 2; ++tj) {
        i64x2 bvv[2][2];
#pragma unroll
        for (int g = 0; g < 2; ++g)
#pragma unroll
            for (int t8 = 0; t8 < 2; ++t8)
                bvv[g][t8] = ldsB[(tj * 4 + gb + g) * 128 + t8 * 64 + lane];

#pragma unroll
        for (int ti = 0; ti < 2; ++ti) {
            if (diagM && ti > tj) continue;      // below-diagonal sub: skip
            const bool dsub = diagM && (ti == tj);

            f32x4 acc[2][2];
#pragma unroll
            for (int i = 0; i < 2; ++i)
#pragma unroll
                for (int j = 0; j < 2; ++j) acc[i][j] = (f32x4){0.f, 0.f, 0.f, 0.f};
#pragma unroll
            for (int t = 0; t < 4; ++t) {        // K-steps of 32
                const int th = t >> 1, tl = t & 1;
                long aL[2], bL[2];
#pragma unroll
                for (int g = 0; g < 2; ++g) {
                    aL[g] = avv[ti][g][th][tl];
                    bL[g] = bvv[g][th][tl];
                }
#pragma unroll
                for (int i = 0; i < 2; ++i)
#pragma unroll
                    for (int j = 0; j < 2; ++j)
                        acc[i][j] = __builtin_amdgcn_mfma_f32_16x16x32_fp8_fp8(
                            aL[i], bL[j], acc[i][j], 0, 0, 0);
            }

            // C/D: col=lane&15, row=(lane>>4)*4+reg (verified)
            float lsum = 0.f;
#pragma unroll
            for (int i = 0; i < 2; ++i) {
                const int rbase = (ga + i) * 16 + quad * 4;   // row in sub-tile
#pragma unroll
                for (int j = 0; j < 2; ++j) {
                    const int cbase = (gb + j) * 16 + colL;   // col in sub-tile
#pragma unroll
                    for (int g = 0; g < 4; ++g) {
                        if (dsub && (rbase + g == cbase)) continue;
                        lsum += EXP2F(fmaf(C, acc[i][j][g], -C));
                    }
                }
            }
            wsum += dsub ? lsum : 2.0f * lsum;   // symmetry weight
        }
    }

#pragma unroll
    for (int o = 32; o > 0; o >>= 1) wsum += __shfl_down(wsum, o, 64);
    __shared__ float red[4];
    __shared__ bool last;
    if (lane == 0) red[w] = wsum;
    __syncthreads();
    if (tid == 0) {
        partials[bk] = red[0] + red[1] + red[2] + red[3];
        // RELEASE publish: wbl2 writeback only — NO buffer_inv / L2 flush.
        last = (__hip_atomic_fetch_add(counter, 1u, __ATOMIC_RELEASE,
                                       __HIP_MEMORY_SCOPE_AGENT) == NMACR - 1);
    }
    __syncthreads();
    if (last) {
        __threadfence();                          // single acquire (one inv)
        double s = 0.0;
        for (int i = tid; i < NMACR; i += 256) s += (double)partials[i];
#pragma unroll
        for (int o = 32; o > 0; o >>= 1) s += __shfl_down(s, o, 64);
        __shared__ double dred[4];
        if (lane == 0) dred[w] = s;
        __syncthreads();
        if (tid == 0)
            out[0] = (float)(10.0 + log(dred[0] + dred[1] + dred[2] + dred[3]));
    }
}

extern "C" void kernel_launch(void* const* d_in, const int* in_sizes, int n_in,
                              void* d_out, int out_size, void* d_ws, size_t ws_size,
                              hipStream_t stream) {
    const float* x = (const float*)d_in[0];
    float* out = (float*)d_out;
    float* partials = (float*)d_ws;                           // 2080 floats @0
    unsigned int* counter = (unsigned int*)((char*)d_ws + 16384);
    unsigned char* Xs = (unsigned char*)d_ws + 131072;        // 1MB fp8 X̂

    normalize_kernel<<<256, 256, 0, stream>>>(x, Xs, counter);
    gram_lse_kernel<<<NMACR, 256, 0, stream>>>((const i64x2*)Xs, partials, counter, out);
}

// Round 15
// 68.450 us; speedup vs baseline: 1.4820x; 1.3532x over previous
//
#include <hip/hip_runtime.h>
#include <hip/hip_fp8.h>
#include <math.h>

// ContrastiveLoss — x (8,128,16,8,8) fp32 (4 MB).
// feats[n,f] = x[b*131072 + f*1024 + r], n=(b<<10)|r, N=8192, F=128.
// loss = 10 + ln( sum_{i!=j} exp(10*dot(x̂_i,x̂_j) - 10) )   (unit rows => s<=10)
//
// Round 24: REVERT TO BEST (exact R11 = 68.14 µs measured). Fusion closed
// after 4 failures: R13's per-block __threadfence buffer_inv flushed L2
// (49 µs gram); R14's release-only atomic still lost ~25 µs to per-block
// wbl2 / same-address far-atomic contention (~12 ns x 2080 blocks). Single-
// counter fusion is structurally bad at this block count; hierarchical
// counters would chase ~3 µs of launch overhead with real regression risk.
// Final measured budget: harness fill 41 (uncontrollable) + launches ~9 +
// norm 1.5 + final 1.5 + gram 14.7 (MFMA floor 5.8 @~1.75GHz + epilogue ~3
// + fabric-bound cold ~6; cold proven insensitive to locality R12,
// occupancy R11, pipelining R5-R7, spills R10).
//
// fp8 swizzled layout (verified R7/R8, absmax 0): row-group rg=n>>4 (16 rows,
// 2KB). 16B chunk (t8*64 + q*16 + r) holds bytes[half*8+j] =
// x̂[row r][k = t8*64 + half*32 + q*8 + j]. C/D: col=lane&15,
// row=(lane>>4)*4+reg (dtype-independent, verified).
//
// ws: partials float[2080] @0; Xs fp8[8192*128] @131072 (1MB).

#define NMACR 2080   // 64*65/2 upper-triangle 128x128 macro-tiles

typedef __attribute__((ext_vector_type(4))) float f32x4;
typedef __attribute__((ext_vector_type(2))) long i64x2;

#if __has_builtin(__builtin_amdgcn_exp2f)
#define EXP2F(x) __builtin_amdgcn_exp2f(x)
#else
#define EXP2F(x) exp2f(x)
#endif

__device__ inline unsigned int pk_fp8(float f0, float f1, float f2, float f3) {
#if __has_builtin(__builtin_amdgcn_cvt_pk_fp8_f32)
    unsigned int r = 0;
    r = __builtin_amdgcn_cvt_pk_fp8_f32(f0, f1, r, false);  // bytes 0,1
    r = __builtin_amdgcn_cvt_pk_fp8_f32(f2, f3, r, true);   // bytes 2,3
    return r;
#else
    union { unsigned char b[4]; unsigned int u; } v;
    v.b[0] = __hip_fp8_e4m3(f0).__x; v.b[1] = __hip_fp8_e4m3(f1).__x;
    v.b[2] = __hip_fp8_e4m3(f2).__x; v.b[3] = __hip_fp8_e4m3(f3).__x;
    return v.u;
#endif
}

// ---------------------------------------------------------------------------
// Kernel 1: normalize + fp8 swizzle. Block = 32 rows (2 row-groups).
// ---------------------------------------------------------------------------
__global__ __launch_bounds__(256)
void normalize_kernel(const float* __restrict__ x, unsigned char* __restrict__ Xs) {
    __shared__ float ldsf[128][33];
    __shared__ float ssred[8][32];
    __shared__ float invs[32];
    const int tid = threadIdx.x;
    const int b  = blockIdx.x >> 5;
    const int r0 = (blockIdx.x & 31) * 32;
    const int rl = tid & 31, fp = tid >> 5;       // row-in-block, f-slot
    const float* px = x + b * 131072 + r0 + rl;
    float ss = 0.f;
#pragma unroll
    for (int j = 0; j < 16; ++j) {
        int f = fp * 16 + j;
        float v = px[f * 1024];
        ldsf[f][rl] = v;
        ss = fmaf(v, v, ss);
    }
    ssred[fp][rl] = ss;
    __syncthreads();
    if (tid < 32) {
        float s = 0.f;
#pragma unroll
        for (int k = 0; k < 8; ++k) s += ssred[k][tid];
        invs[tid] = 1.0f / fmaxf(sqrtf(s), 1e-12f);
    }
    __syncthreads();
    {   // one 16B chunk per thread, consecutive tid -> consecutive chunks
        const int c   = tid;
        const int rgl = c >> 7;                   // local row-group 0..1
        const int cc  = c & 127;                  // chunk within row-group
        const int t8  = (cc >> 6) & 1, q = (cc >> 4) & 3, r = cc & 15;
        const int row = rgl * 16 + r;             // local row 0..31
        const float inv = invs[row];
        union { unsigned int w[4]; int4 v; } u;
#pragma unroll
        for (int half = 0; half < 2; ++half) {
            const int k0 = t8 * 64 + half * 32 + q * 8;
            u.w[half * 2 + 0] = pk_fp8(ldsf[k0 + 0][row] * inv, ldsf[k0 + 1][row] * inv,
                                       ldsf[k0 + 2][row] * inv, ldsf[k0 + 3][row] * inv);
            u.w[half * 2 + 1] = pk_fp8(ldsf[k0 + 4][row] * inv, ldsf[k0 + 5][row] * inv,
                                       ldsf[k0 + 6][row] * inv, ldsf[k0 + 7][row] * inv);
        }
        const int rgg = blockIdx.x * 2 + rgl;     // global row-group
        ((int4*)Xs)[rgg * 128 + cc] = u.v;
    }
}

// ---------------------------------------------------------------------------
// Kernel 2: macro-tile gram, B-only LDS. Block bk -> upper-tri macro (I,J),
// 128x128. avv (private A slices) loaded DIRECTLY from global; B panel
// (16KB, shared) staged in LDS; one barrier; 4 waves x 2x2 sub-tiles.
// ---------------------------------------------------------------------------
__global__ __launch_bounds__(256)
void gram_lse_kernel(const i64x2* __restrict__ Xs, float* __restrict__ partials) {
    const int bk = blockIdx.x;
    const int tid = threadIdx.x;
    const int lane = tid & 63, w = tid >> 6;
    const int ga = (w & 1) * 2;                  // A rg offset within sub-tile
    const int gb = (w >> 1) * 2;                 // B rg offset within sub-tile
    const int quad = lane >> 4, colL = lane & 15;
    const float C = 14.426950408889634f;         // 10*log2(e)

    // closed-form macro decode: tiles_before(I) = I*(129-I)/2  (64 rows)
    int I;
    {
        const int t = bk;
        I = (int)((129.0 - sqrt(16641.0 - 8.0 * (double)t)) * 0.5);
        if (I < 0) I = 0;
        while ((((I + 1) * (128 - I)) >> 1) <= t) ++I;   // tb(I+1) <= t
        while (((I * (129 - I)) >> 1) > t) --I;          // tb(I)   >  t
    }
    const int J = I + (bk - ((I * (129 - I)) >> 1));
    const bool diagM = (I == J);

    // A fragments: DIRECT global loads (private per wave; no LDS relay).
    // rg = 8I + ti*4 + ga + g
    i64x2 avv[2][2][2];
#pragma unroll
    for (int ti = 0; ti < 2; ++ti)
#pragma unroll
        for (int g = 0; g < 2; ++g)
#pragma unroll
            for (int t8 = 0; t8 < 2; ++t8)
                avv[ti][g][t8] =
                    Xs[(I * 8 + ti * 4 + ga + g) * 128 + t8 * 64 + lane];

    // B panel staged in LDS (shared: each rg read by 2 waves, twice)
    __shared__ i64x2 ldsB[1024];                 // 16KB: B panel (8 rgs)
    {
        const i64x2* pb = Xs + J * 1024;         // panel = contiguous Xs slice
#pragma unroll
        for (int i = 0; i < 4; ++i)
            ldsB[tid + i * 256] = pb[tid + i * 256];
    }
    __syncthreads();

    float wsum = 0.f;
#pragma unroll
    for (int tj = 0; tj < 2; ++tj) {
        i64x2 bvv[2][2];
#pragma unroll
        for (int g = 0; g < 2; ++g)
#pragma unroll
            for (int t8 = 0; t8 < 2; ++t8)
                bvv[g][t8] = ldsB[(tj * 4 + gb + g) * 128 + t8 * 64 + lane];

#pragma unroll
        for (int ti = 0; ti < 2; ++ti) {
            if (diagM && ti > tj) continue;      // below-diagonal sub: skip
            const bool dsub = diagM && (ti == tj);

            f32x4 acc[2][2];
#pragma unroll
            for (int i = 0; i < 2; ++i)
#pragma unroll
                for (int j = 0; j < 2; ++j) acc[i][j] = (f32x4){0.f, 0.f, 0.f, 0.f};
#pragma unroll
            for (int t = 0; t < 4; ++t) {        // K-steps of 32
                const int th = t >> 1, tl = t & 1;
                long aL[2], bL[2];
#pragma unroll
                for (int g = 0; g < 2; ++g) {
                    aL[g] = avv[ti][g][th][tl];
                    bL[g] = bvv[g][th][tl];
                }
#pragma unroll
                for (int i = 0; i < 2; ++i)
#pragma unroll
                    for (int j = 0; j < 2; ++j)
                        acc[i][j] = __builtin_amdgcn_mfma_f32_16x16x32_fp8_fp8(
                            aL[i], bL[j], acc[i][j], 0, 0, 0);
            }

            // C/D: col=lane&15, row=(lane>>4)*4+reg (verified)
            float lsum = 0.f;
#pragma unroll
            for (int i = 0; i < 2; ++i) {
                const int rbase = (ga + i) * 16 + quad * 4;   // row in sub-tile
#pragma unroll
                for (int j = 0; j < 2; ++j) {
                    const int cbase = (gb + j) * 16 + colL;   // col in sub-tile
#pragma unroll
                    for (int g = 0; g < 4; ++g) {
                        if (dsub && (rbase + g == cbase)) continue;
                        lsum += EXP2F(fmaf(C, acc[i][j][g], -C));
                    }
                }
            }
            wsum += dsub ? lsum : 2.0f * lsum;   // symmetry weight
        }
    }

#pragma unroll
    for (int o = 32; o > 0; o >>= 1) wsum += __shfl_down(wsum, o, 64);
    __shared__ float red[4];
    if (lane == 0) red[w] = wsum;
    __syncthreads();
    if (tid == 0) partials[bk] = red[0] + red[1] + red[2] + red[3];
}

// ---------------------------------------------------------------------------
// Kernel 3: out = 10 + ln(sum of 2080 partials), f64 accumulation.
// ---------------------------------------------------------------------------
__global__ __launch_bounds__(256)
void final_kernel(const float* __restrict__ partials, float* __restrict__ out) {
    double s = 0.0;
    for (int i = threadIdx.x; i < NMACR; i += 256) s += (double)partials[i];
#pragma unroll
    for (int o = 32; o > 0; o >>= 1) s += __shfl_down(s, o, 64);
    __shared__ double red[4];
    if ((threadIdx.x & 63) == 0) red[threadIdx.x >> 6] = s;
    __syncthreads();
    if (threadIdx.x == 0)
        out[0] = (float)(10.0 + log(red[0] + red[1] + red[2] + red[3]));
}

extern "C" void kernel_launch(void* const* d_in, const int* in_sizes, int n_in,
                              void* d_out, int out_size, void* d_ws, size_t ws_size,
                              hipStream_t stream) {
    const float* x = (const float*)d_in[0];
    float* out = (float*)d_out;
    float* partials = (float*)d_ws;                         // 2080 floats
    unsigned char* Xs = (unsigned char*)d_ws + 131072;      // 1MB fp8 X̂

    normalize_kernel<<<256, 256, 0, stream>>>(x, Xs);
    gram_lse_kernel<<<NMACR, 256, 0, stream>>>((const i64x2*)Xs, partials);
    final_kernel<<<1, 256, 0, stream>>>(partials, out);
}